// Round 3
// baseline (667.213 us; speedup 1.0000x reference)
//
#include <hip/hip_runtime.h>

typedef short short8 __attribute__((ext_vector_type(8)));
typedef short s16x4 __attribute__((ext_vector_type(4)));
typedef float floatx4 __attribute__((ext_vector_type(4)));
typedef unsigned short u16;

#define NN 16384
#define NE 131072
#define NEF_ 128
#define DD 56
#define INV_SQRT3F 0.57735026918962576f
#define PATH_NORMF 0.15811388300841897f

__device__ __forceinline__ float bf2f(u16 u) {
    union { unsigned int i; float f; } v; v.i = ((unsigned int)u) << 16; return v.f;
}
__device__ __forceinline__ u16 f2bf(float f) {
    union { float f; unsigned int i; } v; v.f = f;
    unsigned int r = v.i + 0x7fffu + ((v.i >> 16) & 1u);
    return (u16)(r >> 16);
}

// ---------------- K0: transpose + bf16-ify W1 (128x128) and W2 (128x1600) ----------------
__global__ __launch_bounds__(256) void transpose_w(const float* __restrict__ W1,
                                                   const float* __restrict__ W2,
                                                   u16* __restrict__ W1T,
                                                   u16* __restrict__ W2T) {
    int i = blockIdx.x * 256 + threadIdx.x;   // 864*256 = 221184 = 16384 + 204800 exactly
    if (i < 16384) {
        int n = i >> 7, k = i & 127;
        W1T[i] = f2bf(W1[k * 128 + n]);
    } else {
        int j = i - 16384;
        int n = j >> 7, k = j & 127;
        W2T[j] = f2bf(W2[k * 1600 + n]);
    }
}

// ---------------- K1: fused MLP + tensor product + scatter ----------------
__global__ __launch_bounds__(256) void tpconv(
    const float* __restrict__ node_attr, const float* __restrict__ edge_attr,
    const float* __restrict__ edge_sh, const u16* __restrict__ W1T,
    const float* __restrict__ b1, const u16* __restrict__ W2T,
    const float* __restrict__ b2, const int* __restrict__ eidx,
    float* __restrict__ sums, int* __restrict__ cnt)
{
    __shared__ __align__(16) u16 sA[64 * 136];   // edge_attr tile (bf16), then h tile
    __shared__ __align__(16) u16 sB[64 * 136];   // W1T / W2T chunk (rows = out-cols)
    __shared__ __align__(16) u16 sW[64 * 66];    // w chunk [edge][64 cols]
    __shared__ __align__(16) u16 sF[68 * 64];    // factors [row][edge]: 0..31 xs, 32..39 dot, 40..63 xv, 64 ss, 65..67 sv
    __shared__ int sSrc[64];

    const int t = threadIdx.x;
    const int lane = t & 63;
    const int wv = t >> 6;
    const int m = lane & 15;
    const int q = lane >> 4;
    const int Rb = (wv >> 1) * 32;   // row (edge) base for this wave
    const int Cb = (wv & 1) * 32;    // col base for this wave
    const int e0 = blockIdx.x * 64;

    // stage edge_attr tile (64 x 128 fp32 -> bf16)
    #pragma unroll
    for (int ii = 0; ii < 8; ii++) {
        int cid = t + 256 * ii;          // 0..2047 float4-chunks
        int r = cid >> 5, s = cid & 31;  // 32 float4 per row
        const float* src = &edge_attr[(size_t)(e0 + r) * NEF_ + s * 4];
        s16x4 o;
        o.x = (short)f2bf(src[0]); o.y = (short)f2bf(src[1]);
        o.z = (short)f2bf(src[2]); o.w = (short)f2bf(src[3]);
        *(s16x4*)&sA[r * 136 + s * 4] = o;
    }
    // per-edge factors (wave 0)
    if (t < 64) {
        sSrc[t] = eidx[e0 + t];
        int nd = eidx[NE + e0 + t];
        const float* na = node_attr + (size_t)nd * DD;
        float xs[32], xv[24];
        #pragma unroll
        for (int i = 0; i < 32; i++) xs[i] = na[i];
        #pragma unroll
        for (int i = 0; i < 24; i++) xv[i] = na[32 + i];
        const float* sh = edge_sh + (size_t)(e0 + t) * 4;
        float ss = sh[0], s0 = sh[1], s1 = sh[2], s2 = sh[3];
        #pragma unroll
        for (int i = 0; i < 32; i++) sF[i * 64 + t] = f2bf(xs[i]);
        #pragma unroll
        for (int i = 0; i < 8; i++) {
            float d = (xv[i*3]*s0 + xv[i*3+1]*s1 + xv[i*3+2]*s2) * INV_SQRT3F;
            sF[(32 + i) * 64 + t] = f2bf(d);
        }
        #pragma unroll
        for (int i = 0; i < 24; i++) sF[(40 + i) * 64 + t] = f2bf(xv[i]);
        sF[64 * 64 + t] = f2bf(ss);
        sF[65 * 64 + t] = f2bf(s0);
        sF[66 * 64 + t] = f2bf(s1);
        sF[67 * 64 + t] = f2bf(s2);
    }
    __syncthreads();

    // ---- h = relu(ea @ W1 + b1), two 64-col passes ----
    floatx4 hacc[2][2][2];
    #pragma unroll
    for (int cc = 0; cc < 2; cc++) {
        #pragma unroll
        for (int ii = 0; ii < 4; ii++) {
            int cid = t + 256 * ii;
            int r = cid >> 4, s = cid & 15;
            *(short8*)&sB[r * 136 + s * 8] =
                *(const short8*)&W1T[(size_t)(cc * 64 + r) * 128 + s * 8];
        }
        __syncthreads();
        #pragma unroll
        for (int rt = 0; rt < 2; rt++)
            #pragma unroll
            for (int ct = 0; ct < 2; ct++) {
                float bv = b1[cc * 64 + Cb + ct * 16 + m];
                hacc[cc][rt][ct] = (floatx4){bv, bv, bv, bv};
            }
        #pragma unroll
        for (int k0 = 0; k0 < 128; k0 += 32) {
            short8 a0 = *(const short8*)&sA[(Rb      + m) * 136 + k0 + q * 8];
            short8 a1 = *(const short8*)&sA[(Rb + 16 + m) * 136 + k0 + q * 8];
            short8 bA = *(const short8*)&sB[(Cb      + m) * 136 + k0 + q * 8];
            short8 bB = *(const short8*)&sB[(Cb + 16 + m) * 136 + k0 + q * 8];
            hacc[cc][0][0] = __builtin_amdgcn_mfma_f32_16x16x32_bf16(a0, bA, hacc[cc][0][0], 0, 0, 0);
            hacc[cc][0][1] = __builtin_amdgcn_mfma_f32_16x16x32_bf16(a0, bB, hacc[cc][0][1], 0, 0, 0);
            hacc[cc][1][0] = __builtin_amdgcn_mfma_f32_16x16x32_bf16(a1, bA, hacc[cc][1][0], 0, 0, 0);
            hacc[cc][1][1] = __builtin_amdgcn_mfma_f32_16x16x32_bf16(a1, bB, hacc[cc][1][1], 0, 0, 0);
        }
        __syncthreads();
    }
    // write h (relu, bf16) into sA; C/D layout: row = q*4+r, col = m (m89/m91)
    #pragma unroll
    for (int cc = 0; cc < 2; cc++)
      #pragma unroll
      for (int rt = 0; rt < 2; rt++)
        #pragma unroll
        for (int ct = 0; ct < 2; ct++)
          #pragma unroll
          for (int r = 0; r < 4; r++) {
              int e   = Rb + rt * 16 + q * 4 + r;
              int col = cc * 64 + Cb + ct * 16 + m;
              float v = hacc[cc][rt][ct][r];
              sA[e * 136 + col] = f2bf(v > 0.f ? v : 0.f);
          }
    __syncthreads();

    // ---- chunk loop over 1600 w-cols, 25 chunks of 64 ----
    float tps[16];
    float tpv[4][3];
    #pragma unroll
    for (int i = 0; i < 16; i++) tps[i] = 0.f;
    #pragma unroll
    for (int i = 0; i < 4; i++) { tpv[i][0] = 0.f; tpv[i][1] = 0.f; tpv[i][2] = 0.f; }
    const float ssr = bf2f(sF[64 * 64 + lane]);
    const float sv0 = bf2f(sF[65 * 64 + lane]);
    const float sv1 = bf2f(sF[66 * 64 + lane]);
    const float sv2 = bf2f(sF[67 * 64 + lane]);
    const int jb  = (wv & 1) * 16;   // scalar dim base (waves 0,1)
    const int jvb = (wv & 1) * 4;    // vector jv base (waves 2,3)

    for (int c = 0; c < 25; c++) {
        #pragma unroll
        for (int ii = 0; ii < 4; ii++) {
            int cid = t + 256 * ii;
            int r = cid >> 4, s = cid & 15;
            *(short8*)&sB[r * 136 + s * 8] =
                *(const short8*)&W2T[(size_t)(c * 64 + r) * 128 + s * 8];
        }
        __syncthreads();
        floatx4 acc[2][2];
        #pragma unroll
        for (int rt = 0; rt < 2; rt++)
            #pragma unroll
            for (int ct = 0; ct < 2; ct++) {
                float bv = b2[c * 64 + Cb + ct * 16 + m];
                acc[rt][ct] = (floatx4){bv, bv, bv, bv};
            }
        #pragma unroll
        for (int k0 = 0; k0 < 128; k0 += 32) {
            short8 a0 = *(const short8*)&sA[(Rb      + m) * 136 + k0 + q * 8];
            short8 a1 = *(const short8*)&sA[(Rb + 16 + m) * 136 + k0 + q * 8];
            short8 bA = *(const short8*)&sB[(Cb      + m) * 136 + k0 + q * 8];
            short8 bB = *(const short8*)&sB[(Cb + 16 + m) * 136 + k0 + q * 8];
            acc[0][0] = __builtin_amdgcn_mfma_f32_16x16x32_bf16(a0, bA, acc[0][0], 0, 0, 0);
            acc[0][1] = __builtin_amdgcn_mfma_f32_16x16x32_bf16(a0, bB, acc[0][1], 0, 0, 0);
            acc[1][0] = __builtin_amdgcn_mfma_f32_16x16x32_bf16(a1, bA, acc[1][0], 0, 0, 0);
            acc[1][1] = __builtin_amdgcn_mfma_f32_16x16x32_bf16(a1, bB, acc[1][1], 0, 0, 0);
        }
        #pragma unroll
        for (int rt = 0; rt < 2; rt++)
          #pragma unroll
          for (int ct = 0; ct < 2; ct++)
            #pragma unroll
            for (int r = 0; r < 4; r++) {
                int e  = Rb + rt * 16 + q * 4 + r;
                int lc = Cb + ct * 16 + m;
                sW[e * 66 + lc] = f2bf(acc[rt][ct][r]);
            }
        __syncthreads();

        // consume: regions align to 64-col chunks: ss c<16, vs 16..19, sv 20..23, vv 24
        if (wv < 2) {
            if (c < 20) {
                const int base = (c < 16) ? 0 : 32;
                const int i0   = (c < 16) ? 2 * c : 2 * (c - 16);
                #pragma unroll
                for (int ih = 0; ih < 2; ih++) {
                    float f = bf2f(sF[(base + i0 + ih) * 64 + lane]);
                    if (c < 16) f *= ssr;
                    const u16* wrow = &sW[lane * 66 + ih * 32 + jb];
                    #pragma unroll
                    for (int jj = 0; jj < 16; jj++)
                        tps[jj] += bf2f(wrow[jj]) * f;
                }
            }
        } else {
            if (c >= 20 && c < 24) {
                #pragma unroll
                for (int i8 = 0; i8 < 8; i8++) {
                    int i = 8 * (c - 20) + i8;
                    float xsi = bf2f(sF[i * 64 + lane]);
                    #pragma unroll
                    for (int jj = 0; jj < 4; jj++) {
                        float w = bf2f(sW[lane * 66 + i8 * 8 + jvb + jj]);
                        float t0 = w * xsi;
                        tpv[jj][0] += t0 * sv0;
                        tpv[jj][1] += t0 * sv1;
                        tpv[jj][2] += t0 * sv2;
                    }
                }
            } else if (c == 24) {
                #pragma unroll
                for (int i8 = 0; i8 < 8; i8++) {
                    #pragma unroll
                    for (int jj = 0; jj < 4; jj++) {
                        float w = bf2f(sW[lane * 66 + i8 * 8 + jvb + jj]) * ssr;
                        tpv[jj][0] += w * bf2f(sF[(40 + i8 * 3 + 0) * 64 + lane]);
                        tpv[jj][1] += w * bf2f(sF[(40 + i8 * 3 + 1) * 64 + lane]);
                        tpv[jj][2] += w * bf2f(sF[(40 + i8 * 3 + 2) * 64 + lane]);
                    }
                }
            }
        }
    }

    // scatter (each (edge, dim) owned by exactly one thread)
    const int sn = sSrc[lane];
    if (wv == 0) atomicAdd(&cnt[sn], 1);
    if (wv < 2) {
        #pragma unroll
        for (int jj = 0; jj < 16; jj++)
            atomicAdd(&sums[(size_t)sn * DD + jb + jj], tps[jj] * PATH_NORMF);
    } else {
        #pragma unroll
        for (int jj = 0; jj < 4; jj++)
            #pragma unroll
            for (int mm = 0; mm < 3; mm++)
                atomicAdd(&sums[(size_t)sn * DD + 32 + (jvb + jj) * 3 + mm],
                          tpv[jj][mm] * PATH_NORMF);
    }
}

// ---------------- K2: per-node finalize + BN statistics ----------------
__global__ __launch_bounds__(256) void node_finalize(
    const float* __restrict__ sums, const int* __restrict__ cnt,
    const float* __restrict__ node_attr,
    float* __restrict__ ybuf, float* __restrict__ stats)
{
    const int n = blockIdx.x * 256 + threadIdx.x;   // 64*256 = 16384 exactly
    const int lane = threadIdx.x & 63;
    float inv = 1.f / fmaxf((float)cnt[n], 1.f);
    float y[56];
    #pragma unroll
    for (int d = 0; d < 56; d++) {
        y[d] = sums[(size_t)n * DD + d] * inv + node_attr[(size_t)n * DD + d];
        ybuf[(size_t)n * DD + d] = y[d];
    }
    #pragma unroll
    for (int d = 0; d < 32; d++) {
        float v = y[d], v2 = y[d] * y[d];
        #pragma unroll
        for (int off = 32; off > 0; off >>= 1) {
            v  += __shfl_xor(v,  off, 64);
            v2 += __shfl_xor(v2, off, 64);
        }
        if (lane == 0) { atomicAdd(&stats[d], v); atomicAdd(&stats[32 + d], v2); }
    }
    #pragma unroll
    for (int jv = 0; jv < 8; jv++) {
        float a = y[32 + jv * 3], b = y[33 + jv * 3], c = y[34 + jv * 3];
        float v = a * a + b * b + c * c;
        #pragma unroll
        for (int off = 32; off > 0; off >>= 1) v += __shfl_xor(v, off, 64);
        if (lane == 0) atomicAdd(&stats[64 + jv], v);
    }
}

// ---------------- K3: batch-norm apply + write fp32 output ----------------
__global__ __launch_bounds__(256) void write_out(
    const float* __restrict__ ybuf, const float* __restrict__ stats,
    const float* __restrict__ gamma, const float* __restrict__ beta,
    float* __restrict__ out)
{
    const int i = blockIdx.x * 256 + threadIdx.x;   // 3584*256 = 917504 exactly
    const int n = i / 56;
    const int d = i - n * 56;
    const float invN = 1.f / 16384.f;
    float y = ybuf[i];
    float o;
    if (d < 32) {
        float mn  = stats[d] * invN;
        float var = stats[32 + d] * invN - mn * mn;
        o = (y - mn) * rsqrtf(var + 1e-5f) * gamma[d] + beta[d];
    } else {
        int jv = (d - 32) / 3;
        float vm = stats[64 + jv] * invN;
        o = y * rsqrtf(vm + 1e-5f) * gamma[32 + jv];
    }
    out[i] = o;
}

// ---------------- launch ----------------
extern "C" void kernel_launch(void* const* d_in, const int* in_sizes, int n_in,
                              void* d_out, int out_size, void* d_ws, size_t ws_size,
                              hipStream_t stream)
{
    const float* node_attr = (const float*)d_in[0];
    const float* edge_attr = (const float*)d_in[1];
    const float* edge_sh   = (const float*)d_in[2];
    const float* W1        = (const float*)d_in[3];
    const float* b1        = (const float*)d_in[4];
    const float* W2        = (const float*)d_in[5];
    const float* b2        = (const float*)d_in[6];
    const float* gamma     = (const float*)d_in[7];
    const float* beta      = (const float*)d_in[8];
    const int*   eidx      = (const int*)d_in[9];

    char* ws = (char*)d_ws;
    u16*   W1T   = (u16*)(ws);                 //  32768 B
    u16*   W2T   = (u16*)(ws + 32768);         // 409600 B
    float* sums  = (float*)(ws + 442368);      // 16384*56*4 = 3670016 B
    int*   cnt   = (int*)(ws + 4112384);       // 65536 B
    float* stats = (float*)(ws + 4177920);     // 288 B
    float* ybuf  = (float*)(ws + 4178208);     // 3670016 B  (total ~7.85 MB)

    (void)hipMemsetAsync(ws + 442368, 0, 3670016 + 65536 + 288, stream);
    hipLaunchKernelGGL(transpose_w, dim3(864), dim3(256), 0, stream, W1, W2, W1T, W2T);
    hipLaunchKernelGGL(tpconv, dim3(2048), dim3(256), 0, stream,
                       node_attr, edge_attr, edge_sh, W1T, b1, W2T, b2, eidx, sums, cnt);
    hipLaunchKernelGGL(node_finalize, dim3(64), dim3(256), 0, stream,
                       sums, cnt, node_attr, ybuf, stats);
    hipLaunchKernelGGL(write_out, dim3(3584), dim3(256), 0, stream,
                       ybuf, stats, gamma, beta, (float*)d_out);
}

// Round 4
// 325.023 us; speedup vs baseline: 2.0528x; 2.0528x over previous
//
#include <hip/hip_runtime.h>

typedef short short8 __attribute__((ext_vector_type(8)));
typedef float floatx4 __attribute__((ext_vector_type(4)));
typedef unsigned short u16;

#define NN 16384
#define NE 131072
#define NEF_ 128
#define DD 56
#define INV_SQRT3F 0.57735026918962576f
#define PATH_NORMF 0.15811388300841897f

__device__ __forceinline__ float bf2f(u16 u) {
    union { unsigned int i; float f; } v; v.i = ((unsigned int)u) << 16; return v.f;
}
__device__ __forceinline__ u16 f2bf(float f) {
    union { float f; unsigned int i; } v; v.f = f;
    unsigned int r = v.i + 0x7fffu + ((v.i >> 16) & 1u);
    return (u16)(r >> 16);
}

// ---------------- K0: transpose + bf16-ify W1 (128x128) and W2 (128x1600) ----------------
__global__ __launch_bounds__(256) void transpose_w(const float* __restrict__ W1,
                                                   const float* __restrict__ W2,
                                                   u16* __restrict__ W1T,
                                                   u16* __restrict__ W2T) {
    int i = blockIdx.x * 256 + threadIdx.x;   // 864*256 = 221184 = 16384 + 204800
    if (i < 16384) {
        int n = i >> 7, k = i & 127;
        W1T[i] = f2bf(W1[k * 128 + n]);
    } else {
        int j = i - 16384;
        int n = j >> 7, k = j & 127;
        W2T[j] = f2bf(W2[k * 1600 + n]);
    }
}

// ---------------- CSR build: histogram, scan, scatter ----------------
__global__ __launch_bounds__(256) void edge_deg(const int* __restrict__ eidx,
                                                int* __restrict__ deg) {
    int e = blockIdx.x * 256 + threadIdx.x;   // 512 blocks
    atomicAdd(&deg[eidx[e]], 1);
}

__global__ __launch_bounds__(1024) void deg_scan(const int* __restrict__ deg,
                                                 int* __restrict__ row_start,
                                                 int* __restrict__ cursor) {
    __shared__ int part[1024];
    const int t = threadIdx.x;
    const int base = t * 16;
    int loc[16];
    int s = 0;
    #pragma unroll
    for (int i = 0; i < 16; i++) { loc[i] = s; s += deg[base + i]; }
    part[t] = s;
    __syncthreads();
    for (int off = 1; off < 1024; off <<= 1) {
        int v = (t >= off) ? part[t - off] : 0;
        __syncthreads();
        part[t] += v;
        __syncthreads();
    }
    int pre = (t == 0) ? 0 : part[t - 1];
    #pragma unroll
    for (int i = 0; i < 16; i++) {
        int v = pre + loc[i];
        row_start[base + i] = v;
        cursor[base + i] = v;
    }
    if (t == 1023) row_start[16384] = pre + s;
}

__global__ __launch_bounds__(256) void edge_scatter(const int* __restrict__ eidx,
                                                    int* __restrict__ cursor,
                                                    int* __restrict__ edge_order) {
    int e = blockIdx.x * 256 + threadIdx.x;   // 512 blocks
    int p = atomicAdd(&cursor[eidx[e]], 1);
    edge_order[p] = e;
}

// ---------------- K2: fused MLP + tensor product -> per-edge tp ----------------
__global__ __launch_bounds__(256) void tpconv(
    const float* __restrict__ node_attr, const float* __restrict__ edge_attr,
    const float* __restrict__ edge_sh, const u16* __restrict__ W1T,
    const float* __restrict__ b1, const u16* __restrict__ W2T,
    const float* __restrict__ b2, const int* __restrict__ eidx,
    float* __restrict__ tp)
{
    __shared__ __align__(16) u16 sA[64 * 136];   // edge_attr tile (bf16), then h tile
    __shared__ __align__(16) u16 sB[64 * 136];   // W1T / W2T chunk (rows = out-cols)
    __shared__ __align__(16) u16 sW[64 * 66];    // w chunk [edge][64 cols]
    __shared__ __align__(16) u16 sF[68 * 64];    // factors [row][edge]

    const int t = threadIdx.x;
    const int lane = t & 63;
    const int wv = t >> 6;
    const int m = lane & 15;
    const int q = lane >> 4;
    const int Rb = (wv >> 1) * 32;
    const int Cb = (wv & 1) * 32;
    const int e0 = blockIdx.x * 64;
    const int str = t >> 4;      // staging row base (+16*ii)
    const int stc = (t & 15) * 8;

    // stage edge_attr tile (64 x 128 fp32 -> bf16)
    #pragma unroll
    for (int ii = 0; ii < 8; ii++) {
        int cid = t + 256 * ii;
        int r = cid >> 5, s = cid & 31;
        const float* src = &edge_attr[(size_t)(e0 + r) * NEF_ + s * 4];
        u16 o0 = f2bf(src[0]), o1 = f2bf(src[1]), o2 = f2bf(src[2]), o3 = f2bf(src[3]);
        short8* dst = (short8*)&sA[r * 136 + s * 4];
        ((u16*)dst)[0] = o0; ((u16*)dst)[1] = o1; ((u16*)dst)[2] = o2; ((u16*)dst)[3] = o3;
    }
    // per-edge factors (wave 0)
    if (t < 64) {
        int nd = eidx[NE + e0 + t];
        const float* na = node_attr + (size_t)nd * DD;
        const float* sh = edge_sh + (size_t)(e0 + t) * 4;
        float ss = sh[0], s0 = sh[1], s1 = sh[2], s2 = sh[3];
        #pragma unroll
        for (int i = 0; i < 32; i++) sF[i * 64 + t] = f2bf(na[i]);
        #pragma unroll
        for (int i = 0; i < 8; i++) {
            float d = (na[32+i*3]*s0 + na[33+i*3]*s1 + na[34+i*3]*s2) * INV_SQRT3F;
            sF[(32 + i) * 64 + t] = f2bf(d);
        }
        #pragma unroll
        for (int i = 0; i < 24; i++) sF[(40 + i) * 64 + t] = f2bf(na[32 + i]);
        sF[64 * 64 + t] = f2bf(ss);
        sF[65 * 64 + t] = f2bf(s0);
        sF[66 * 64 + t] = f2bf(s1);
        sF[67 * 64 + t] = f2bf(s2);
    }
    __syncthreads();

    // ---- h = relu(ea @ W1 + b1), two 64-col passes ----
    floatx4 hacc[2][2][2];
    #pragma unroll
    for (int cc = 0; cc < 2; cc++) {
        #pragma unroll
        for (int ii = 0; ii < 4; ii++)
            *(short8*)&sB[(str + 16 * ii) * 136 + stc] =
                *(const short8*)&W1T[(size_t)(cc * 64 + str + 16 * ii) * 128 + stc];
        __syncthreads();
        #pragma unroll
        for (int rt = 0; rt < 2; rt++)
            #pragma unroll
            for (int ct = 0; ct < 2; ct++) {
                float bv = b1[cc * 64 + Cb + ct * 16 + m];
                hacc[cc][rt][ct] = (floatx4){bv, bv, bv, bv};
            }
        #pragma unroll
        for (int k0 = 0; k0 < 128; k0 += 32) {
            short8 a0 = *(const short8*)&sA[(Rb      + m) * 136 + k0 + q * 8];
            short8 a1 = *(const short8*)&sA[(Rb + 16 + m) * 136 + k0 + q * 8];
            short8 bA = *(const short8*)&sB[(Cb      + m) * 136 + k0 + q * 8];
            short8 bB = *(const short8*)&sB[(Cb + 16 + m) * 136 + k0 + q * 8];
            hacc[cc][0][0] = __builtin_amdgcn_mfma_f32_16x16x32_bf16(a0, bA, hacc[cc][0][0], 0, 0, 0);
            hacc[cc][0][1] = __builtin_amdgcn_mfma_f32_16x16x32_bf16(a0, bB, hacc[cc][0][1], 0, 0, 0);
            hacc[cc][1][0] = __builtin_amdgcn_mfma_f32_16x16x32_bf16(a1, bA, hacc[cc][1][0], 0, 0, 0);
            hacc[cc][1][1] = __builtin_amdgcn_mfma_f32_16x16x32_bf16(a1, bB, hacc[cc][1][1], 0, 0, 0);
        }
        __syncthreads();
    }
    // write h (relu, bf16) into sA; C/D layout: row = q*4+r, col = m
    #pragma unroll
    for (int cc = 0; cc < 2; cc++)
      #pragma unroll
      for (int rt = 0; rt < 2; rt++)
        #pragma unroll
        for (int ct = 0; ct < 2; ct++)
          #pragma unroll
          for (int r = 0; r < 4; r++) {
              int e   = Rb + rt * 16 + q * 4 + r;
              int col = cc * 64 + Cb + ct * 16 + m;
              float v = hacc[cc][rt][ct][r];
              sA[e * 136 + col] = f2bf(v > 0.f ? v : 0.f);
          }
    __syncthreads();

    // ---- chunk loop, software-pipelined W2T staging ----
    float tps[16];
    float tpv[4][3];
    #pragma unroll
    for (int i = 0; i < 16; i++) tps[i] = 0.f;
    #pragma unroll
    for (int i = 0; i < 4; i++) { tpv[i][0] = 0.f; tpv[i][1] = 0.f; tpv[i][2] = 0.f; }
    const float ssr = bf2f(sF[64 * 64 + lane]);
    const float sv0 = bf2f(sF[65 * 64 + lane]);
    const float sv1 = bf2f(sF[66 * 64 + lane]);
    const float sv2 = bf2f(sF[67 * 64 + lane]);
    const int jb  = (wv & 1) * 16;
    const int jvb = (wv & 1) * 4;

    short8 pre[4];
    float pb0, pb1;
    #pragma unroll
    for (int ii = 0; ii < 4; ii++)
        pre[ii] = *(const short8*)&W2T[(size_t)(str + 16 * ii) * 128 + stc];
    pb0 = b2[Cb + m];
    pb1 = b2[Cb + 16 + m];

    for (int c = 0; c < 25; c++) {
        // commit prefetched chunk to LDS (sB free: all MFMA reads done pre-barrier-B of c-1)
        #pragma unroll
        for (int ii = 0; ii < 4; ii++)
            *(short8*)&sB[(str + 16 * ii) * 136 + stc] = pre[ii];
        float cb0 = pb0, cb1 = pb1;
        if (c < 24) {
            #pragma unroll
            for (int ii = 0; ii < 4; ii++)
                pre[ii] = *(const short8*)&W2T[(size_t)((c + 1) * 64 + str + 16 * ii) * 128 + stc];
            pb0 = b2[(c + 1) * 64 + Cb + m];
            pb1 = b2[(c + 1) * 64 + Cb + 16 + m];
        }
        __syncthreads();   // barrier A: sB ready; also guards sW vs prev consume

        floatx4 acc[2][2];
        #pragma unroll
        for (int rt = 0; rt < 2; rt++) {
            acc[rt][0] = (floatx4){cb0, cb0, cb0, cb0};
            acc[rt][1] = (floatx4){cb1, cb1, cb1, cb1};
        }
        #pragma unroll
        for (int k0 = 0; k0 < 128; k0 += 32) {
            short8 a0 = *(const short8*)&sA[(Rb      + m) * 136 + k0 + q * 8];
            short8 a1 = *(const short8*)&sA[(Rb + 16 + m) * 136 + k0 + q * 8];
            short8 bA = *(const short8*)&sB[(Cb      + m) * 136 + k0 + q * 8];
            short8 bB = *(const short8*)&sB[(Cb + 16 + m) * 136 + k0 + q * 8];
            acc[0][0] = __builtin_amdgcn_mfma_f32_16x16x32_bf16(a0, bA, acc[0][0], 0, 0, 0);
            acc[0][1] = __builtin_amdgcn_mfma_f32_16x16x32_bf16(a0, bB, acc[0][1], 0, 0, 0);
            acc[1][0] = __builtin_amdgcn_mfma_f32_16x16x32_bf16(a1, bA, acc[1][0], 0, 0, 0);
            acc[1][1] = __builtin_amdgcn_mfma_f32_16x16x32_bf16(a1, bB, acc[1][1], 0, 0, 0);
        }
        #pragma unroll
        for (int rt = 0; rt < 2; rt++)
          #pragma unroll
          for (int ct = 0; ct < 2; ct++)
            #pragma unroll
            for (int r = 0; r < 4; r++) {
                int e  = Rb + rt * 16 + q * 4 + r;
                int lc = Cb + ct * 16 + m;
                sW[e * 66 + lc] = f2bf(acc[rt][ct][r]);
            }
        __syncthreads();   // barrier B: sW ready

        // consume: ss c<16, vs 16..19, sv 20..23, vv 24
        if (wv < 2) {
            if (c < 20) {
                const int base = (c < 16) ? 0 : 32;
                const int i0   = (c < 16) ? 2 * c : 2 * (c - 16);
                #pragma unroll
                for (int ih = 0; ih < 2; ih++) {
                    float f = bf2f(sF[(base + i0 + ih) * 64 + lane]);
                    if (c < 16) f *= ssr;
                    const u16* wrow = &sW[lane * 66 + ih * 32 + jb];
                    #pragma unroll
                    for (int jj = 0; jj < 16; jj++)
                        tps[jj] += bf2f(wrow[jj]) * f;
                }
            }
        } else {
            if (c >= 20 && c < 24) {
                #pragma unroll
                for (int i8 = 0; i8 < 8; i8++) {
                    int i = 8 * (c - 20) + i8;
                    float xsi = bf2f(sF[i * 64 + lane]);
                    #pragma unroll
                    for (int jj = 0; jj < 4; jj++) {
                        float w = bf2f(sW[lane * 66 + i8 * 8 + jvb + jj]);
                        float t0 = w * xsi;
                        tpv[jj][0] += t0 * sv0;
                        tpv[jj][1] += t0 * sv1;
                        tpv[jj][2] += t0 * sv2;
                    }
                }
            } else if (c == 24) {
                #pragma unroll
                for (int i8 = 0; i8 < 8; i8++) {
                    #pragma unroll
                    for (int jj = 0; jj < 4; jj++) {
                        float w = bf2f(sW[lane * 66 + i8 * 8 + jvb + jj]) * ssr;
                        tpv[jj][0] += w * bf2f(sF[(40 + i8 * 3 + 0) * 64 + lane]);
                        tpv[jj][1] += w * bf2f(sF[(40 + i8 * 3 + 1) * 64 + lane]);
                        tpv[jj][2] += w * bf2f(sF[(40 + i8 * 3 + 2) * 64 + lane]);
                    }
                }
            }
        }
    }

    // plain vectorized stores (each (edge,dim) owned by exactly one thread)
    const size_t eg = (size_t)(e0 + lane);
    if (wv < 2) {
        #pragma unroll
        for (int k = 0; k < 4; k++) {
            floatx4 o = { tps[4*k]   * PATH_NORMF, tps[4*k+1] * PATH_NORMF,
                          tps[4*k+2] * PATH_NORMF, tps[4*k+3] * PATH_NORMF };
            *(floatx4*)&tp[eg * DD + jb + 4 * k] = o;
        }
    } else {
        float f[12];
        #pragma unroll
        for (int jj = 0; jj < 4; jj++)
            #pragma unroll
            for (int mm = 0; mm < 3; mm++)
                f[jj * 3 + mm] = tpv[jj][mm] * PATH_NORMF;
        #pragma unroll
        for (int k = 0; k < 3; k++) {
            floatx4 o = { f[4*k], f[4*k+1], f[4*k+2], f[4*k+3] };
            *(floatx4*)&tp[eg * DD + 32 + jvb * 3 + 4 * k] = o;
        }
    }
}

// ---------------- K3: CSR gather segment-mean + residual ----------------
__global__ __launch_bounds__(256) void gather_finalize(
    const float* __restrict__ tp, const int* __restrict__ row_start,
    const int* __restrict__ edge_order, const float* __restrict__ node_attr,
    float* __restrict__ ybuf)
{
    const int wv = threadIdx.x >> 6, lane = threadIdx.x & 63;
    const int n = blockIdx.x * 4 + wv;    // 4096 blocks
    const int beg = row_start[n], end = row_start[n + 1];
    if (lane < 56) {
        float acc = 0.f;
        for (int p = beg; p < end; p++) {
            int e = edge_order[p];
            acc += tp[(size_t)e * DD + lane];
        }
        float inv = 1.f / fmaxf((float)(end - beg), 1.f);
        float y = acc * inv + node_attr[(size_t)n * DD + lane];
        ybuf[(size_t)n * DD + lane] = y;
    }
}

// ---------------- K4: BN statistics (no atomics) ----------------
__global__ __launch_bounds__(256) void bn_stats(const float* __restrict__ ybuf,
                                                float* __restrict__ stats)
{
    __shared__ float red[256];
    const int d = blockIdx.x;   // 0..71
    const int t = threadIdx.x;
    float a = 0.f;
    if (d < 32) {
        for (int n = t; n < NN; n += 256) a += ybuf[(size_t)n * DD + d];
    } else if (d < 64) {
        int dd = d - 32;
        for (int n = t; n < NN; n += 256) {
            float v = ybuf[(size_t)n * DD + dd];
            a += v * v;
        }
    } else {
        int jv = d - 64;
        for (int n = t; n < NN; n += 256) {
            float v0 = ybuf[(size_t)n * DD + 32 + jv * 3];
            float v1 = ybuf[(size_t)n * DD + 33 + jv * 3];
            float v2 = ybuf[(size_t)n * DD + 34 + jv * 3];
            a += v0 * v0 + v1 * v1 + v2 * v2;
        }
    }
    red[t] = a;
    __syncthreads();
    for (int off = 128; off > 0; off >>= 1) {
        if (t < off) red[t] += red[t + off];
        __syncthreads();
    }
    if (t == 0) stats[d] = red[0] * (1.f / 16384.f);
}

// ---------------- K5: batch-norm apply + write fp32 output ----------------
__global__ __launch_bounds__(256) void bn_apply(
    const float* __restrict__ ybuf, const float* __restrict__ stats,
    const float* __restrict__ gamma, const float* __restrict__ beta,
    float* __restrict__ out)
{
    const int i = blockIdx.x * 256 + threadIdx.x;   // 3584*256 = 917504
    const int n = i / 56;
    const int d = i - n * 56;
    float y = ybuf[i];
    float o;
    if (d < 32) {
        float mn  = stats[d];
        float var = stats[32 + d] - mn * mn;
        o = (y - mn) * rsqrtf(var + 1e-5f) * gamma[d] + beta[d];
    } else {
        int jv = (d - 32) / 3;
        o = y * rsqrtf(stats[64 + jv] + 1e-5f) * gamma[32 + jv];
    }
    out[i] = o;
}

// ---------------- launch ----------------
extern "C" void kernel_launch(void* const* d_in, const int* in_sizes, int n_in,
                              void* d_out, int out_size, void* d_ws, size_t ws_size,
                              hipStream_t stream)
{
    const float* node_attr = (const float*)d_in[0];
    const float* edge_attr = (const float*)d_in[1];
    const float* edge_sh   = (const float*)d_in[2];
    const float* W1        = (const float*)d_in[3];
    const float* b1        = (const float*)d_in[4];
    const float* W2        = (const float*)d_in[5];
    const float* b2        = (const float*)d_in[6];
    const float* gamma     = (const float*)d_in[7];
    const float* beta      = (const float*)d_in[8];
    const int*   eidx      = (const int*)d_in[9];

    char* ws = (char*)d_ws;
    u16*   W1T        = (u16*)(ws);                  // 32768 B
    u16*   W2T        = (u16*)(ws + 32768);          // 409600 B  -> 442368
    int*   deg        = (int*)(ws + 442368);         // 65536     -> 507904
    int*   row_start  = (int*)(ws + 507904);         // 65792     -> 573696
    int*   cursor     = (int*)(ws + 573696);         // 65536     -> 639232
    int*   edge_order = (int*)(ws + 639232);         // 524288    -> 1163520
    float* stats      = (float*)(ws + 1163520);      // 512       -> 1164032
    float* tp         = (float*)(ws + 1164032);      // 29360128  -> 30524160
    float* ybuf       = (float*)(ws + 30524160);     // 3670016   -> 34194176 (~34.2 MB)

    (void)hipMemsetAsync(deg, 0, 65536, stream);
    hipLaunchKernelGGL(transpose_w,     dim3(864),  dim3(256),  0, stream, W1, W2, W1T, W2T);
    hipLaunchKernelGGL(edge_deg,        dim3(512),  dim3(256),  0, stream, eidx, deg);
    hipLaunchKernelGGL(deg_scan,        dim3(1),    dim3(1024), 0, stream, deg, row_start, cursor);
    hipLaunchKernelGGL(edge_scatter,    dim3(512),  dim3(256),  0, stream, eidx, cursor, edge_order);
    hipLaunchKernelGGL(tpconv,          dim3(2048), dim3(256),  0, stream,
                       node_attr, edge_attr, edge_sh, W1T, b1, W2T, b2, eidx, tp);
    hipLaunchKernelGGL(gather_finalize, dim3(4096), dim3(256),  0, stream,
                       tp, row_start, edge_order, node_attr, ybuf);
    hipLaunchKernelGGL(bn_stats,        dim3(72),   dim3(256),  0, stream, ybuf, stats);
    hipLaunchKernelGGL(bn_apply,        dim3(3584), dim3(256),  0, stream,
                       ybuf, stats, gamma, beta, (float*)d_out);
}